// Round 12
// baseline (160.850 us; speedup 1.0000x reference)
//
#include <hip/hip_runtime.h>
#include <hip/hip_bf16.h>
#include <cstdint>
#include <cstddef>

// Problem constants
#define BDIM   32768
#define KDIM   2048
#define NDIM   128
#define VHEADS 20
#define PDIM   6
#define RLORA  10

#define BM     16
#define BK     32
#define NCH    (KDIM / BK)                  // 64 chunks of K=32
#define OUT_ELEMS   (BDIM * VHEADS * PDIM)  // 3932160
#define WS_W_BYTES  (KDIM * NDIM * 2)       // 524288

typedef __attribute__((ext_vector_type(8))) __bf16 bf16x8;
typedef __attribute__((ext_vector_type(4))) float f32x4;
typedef __attribute__((ext_vector_type(2))) float f32x2;
typedef __attribute__((ext_vector_type(4))) unsigned int u32x4;

union FragU { bf16x8 b; u32x4 u; };

__device__ __forceinline__ unsigned int cvt_pk_bf16(float lo, float hi) {
  unsigned int r;
  asm("v_cvt_pk_bf16_f32 %0, %1, %2" : "=v"(r) : "v"(lo), "v"(hi));
  return r;
}

__device__ __forceinline__ float fast_tanh(float x) {
  float ax = fabsf(x);
  float e  = __expf(-2.0f * ax);
  float t  = __fdividef(1.0f - e, 1.0f + e);
  return copysignf(t, x);
}

#define SBAR() __builtin_amdgcn_sched_barrier(0)
// Unmovable, unshrinkable 16B global load with literal offset.
#define GL16(dst, addr, OFFSTR) \
  asm volatile("global_load_dwordx4 %0, %1, off offset:" OFFSTR \
               : "=v"(dst) : "v"(addr))

// ---------------------------------------------------------------------------
// k0: pack We1 f32[2048][128] -> bf16, PER-K32-CHUNK-CONTIGUOUS fragments:
//   byte offset ((c*8 + nt)*64 + lane)*16 holds the 8 bf16 for
//   n = nt*16 + (lane&15), k = c*32 + (lane>>4)*8 + j  (j = 0..7).
//   So in k1, chunk c's 8 B-fragments live at lane_base + c*8192 + nt*1024:
//   one base register + literal offsets nt*1024-3584 covers all 8.
// Also M = lora_A @ lora_B ([2][120]).
// ---------------------------------------------------------------------------
__global__ __launch_bounds__(256)
void k0_pack(const float* __restrict__ We1,
             const float* __restrict__ lA,
             const float* __restrict__ lB,
             unsigned short* __restrict__ wsw,
             float* __restrict__ wsM) {
  if (blockIdx.x == 128) {
    int t = threadIdx.x;
    if (t < 2 * VHEADS * PDIM) {
      int d  = t / (VHEADS * PDIM);
      int vp = t - d * (VHEADS * PDIM);
      float s = 0.f;
#pragma unroll
      for (int r = 0; r < RLORA; ++r)
        s = fmaf(lA[d * RLORA + r], lB[r * (VHEADS * PDIM) + vp], s);
      wsM[t] = s;  // layout [d][vp]
    }
    return;
  }
  int t    = blockIdx.x * 256 + threadIdx.x;  // 0..32767
  int lane = t & 63;
  int g    = t >> 6;        // 0..511
  int nt   = g & 7;
  int c    = g >> 3;        // 0..63
  int n    = nt * 16 + (lane & 15);
  int kb   = c * BK + (lane >> 4) * 8;

  unsigned int u[4];
#pragma unroll
  for (int q = 0; q < 4; ++q) {
    float f0 = We1[(size_t)(kb + 2 * q + 0) * NDIM + n];
    float f1 = We1[(size_t)(kb + 2 * q + 1) * NDIM + n];
    __hip_bfloat16 h0 = __float2bfloat16(f0);
    __hip_bfloat16 h1 = __float2bfloat16(f1);
    u[q] = (unsigned int)*reinterpret_cast<unsigned short*>(&h0) |
           ((unsigned int)*reinterpret_cast<unsigned short*>(&h1) << 16);
  }
  *reinterpret_cast<u32x4*>(wsw + (size_t)t * 8) = u32x4{u[0], u[1], u[2], u[3]};
}

// ---------------------------------------------------------------------------
// k1: fused encoder + heads.  INLINE-ASM register pipeline.
//   2048 blocks x 64 threads (1 wave, 16 rows, full K).  No LDS / barriers
//   in the loop.  Per K32 chunk: 2 A dwordx4 (x, f32) + 8 B dwordx4
//   (bf16 pack, L2-resident) issued as asm volatile -> compiler cannot
//   sink, dedupe, or spill-shrink them.  Double-buffered E/O register sets;
//   steady state keeps 20 loads (2 chunks) in flight; counted
//   s_waitcnt vmcnt(10) + sched_barrier(0) (rule #18) gates each COMPUTE.
//   Epilogue: shfl z-reduce -> z; heads (slot = lane>>4, 5 heads each).
// ---------------------------------------------------------------------------
__global__ __launch_bounds__(64)
void k1_fused(const float* __restrict__ x,
              const unsigned short* __restrict__ wp,
              const float* __restrict__ be1,
              const float* __restrict__ We2,
              const float* __restrict__ be2,
              const float* __restrict__ W1,
              const float* __restrict__ b1,
              const float* __restrict__ W2,
              const float* __restrict__ b2,
              const float* __restrict__ M,
              float* __restrict__ out,
              float* __restrict__ zout) {
  __shared__ float zf[32];

  const int lane = threadIdx.x;   // 0..63
  const int l15  = lane & 15;
  const int kgrp = lane >> 4;     // 0..3
  const int blk  = blockIdx.x;

  // A: lane's own fragment: row = blk*16 + l15, k = c*32 + kgrp*8 + {0..7}
  const char* ap = (const char*)(x + (size_t)(blk * BM + l15) * KDIM + kgrp * 8);
  // B: lane base + 3584 so offsets nt*1024-3584 span all 8 fragments
  const char* bb = (const char*)wp + lane * 16 + 3584;

  f32x4 acc[8];
#pragma unroll
  for (int i = 0; i < 8; ++i) acc[i] = f32x4{0.f, 0.f, 0.f, 0.f};

  f32x4 aE0, aE1, aO0, aO1;
  FragU bE[8], bO[8];

  auto ISSUE = [&](f32x4& a0, f32x4& a1, FragU* B) {
    GL16(a0, ap, "0");
    GL16(a1, ap, "16");
    GL16(B[0].u, bb, "-3584");
    GL16(B[1].u, bb, "-2560");
    GL16(B[2].u, bb, "-1536");
    GL16(B[3].u, bb, "-512");
    GL16(B[4].u, bb, "512");
    GL16(B[5].u, bb, "1536");
    GL16(B[6].u, bb, "2560");
    GL16(B[7].u, bb, "3584");
    ap += BK * 4;     // next chunk of this row
    bb += 8192;       // next chunk of the pack
  };

  auto COMP = [&](const f32x4& a0, const f32x4& a1, const FragU* B) {
    FragU a;
    a.u = u32x4{cvt_pk_bf16(a0.x, a0.y), cvt_pk_bf16(a0.z, a0.w),
                cvt_pk_bf16(a1.x, a1.y), cvt_pk_bf16(a1.z, a1.w)};
#pragma unroll
    for (int nt = 0; nt < 8; ++nt)
      acc[nt] = __builtin_amdgcn_mfma_f32_16x16x32_bf16(a.b, B[nt].b, acc[nt], 0, 0, 0);
  };

  // prologue: chunk 0 in flight (10 loads)
  ISSUE(aE0, aE1, bE);

#pragma unroll 1
  for (int cc = 0; cc < NCH / 2 - 1; ++cc) {   // 31 iters: chunks 2cc+1, 2cc+2
    ISSUE(aO0, aO1, bO);                        // 20 outstanding
    asm volatile("s_waitcnt vmcnt(10)");        // chunk 2cc landed
    SBAR();
    COMP(aE0, aE1, bE);
    SBAR();
    ISSUE(aE0, aE1, bE);                        // 20 outstanding
    asm volatile("s_waitcnt vmcnt(10)");        // chunk 2cc+1 landed
    SBAR();
    COMP(aO0, aO1, bO);
    SBAR();
  }
  // epilogue: chunks 62, 63
  ISSUE(aO0, aO1, bO);                          // chunk 63 in flight
  asm volatile("s_waitcnt vmcnt(10)");          // chunk 62 landed
  SBAR();
  COMP(aE0, aE1, bE);
  SBAR();
  asm volatile("s_waitcnt vmcnt(0)");           // chunk 63 landed
  SBAR();
  COMP(aO0, aO1, bO);

  // ---- epilogue: +be1, relu, @We2, +be2 -> z for this wave's 16 rows
  float part[4][2];
#pragma unroll
  for (int j = 0; j < 4; ++j) { part[j][0] = 0.f; part[j][1] = 0.f; }
#pragma unroll
  for (int nt = 0; nt < 8; ++nt) {
    int col = nt * 16 + l15;
    float bb1v = be1[col];
    float w0 = We2[col * 2 + 0];
    float w1 = We2[col * 2 + 1];
#pragma unroll
    for (int j = 0; j < 4; ++j) {
      float h = acc[nt][j] + bb1v;
      h = h > 0.f ? h : 0.f;
      part[j][0] = fmaf(h, w0, part[j][0]);
      part[j][1] = fmaf(h, w1, part[j][1]);
    }
  }
#pragma unroll
  for (int m = 1; m < 16; m <<= 1) {
#pragma unroll
    for (int j = 0; j < 4; ++j) {
      part[j][0] += __shfl_xor(part[j][0], m, 64);
      part[j][1] += __shfl_xor(part[j][1], m, 64);
    }
  }
  if (l15 == 0) {
    float bz0 = be2[0], bz1 = be2[1];
#pragma unroll
    for (int j = 0; j < 4; ++j) {
      int rl = kgrp * 4 + j;   // C row = (lane>>4)*4 + reg
      float zz0 = part[j][0] + bz0;
      float zz1 = part[j][1] + bz1;
      zf[rl * 2 + 0] = zz0;
      zf[rl * 2 + 1] = zz1;
      f32x2 zz = {zz0, zz1};
      *(f32x2*)(zout + (size_t)(blk * BM + rl) * 2) = zz;
    }
  }
  __syncthreads();   // 1-wave block: orders LDS z write -> read

  // ---- heads: row = lane&15, slot = lane>>4; head v = i*4 + slot
  const int srow = l15;
  const int slot = kgrp;
  float z0 = zf[srow * 2 + 0];
  float z1 = zf[srow * 2 + 1];
  float* orow = out + (size_t)(blk * BM + srow) * (VHEADS * PDIM);

#pragma unroll 1
  for (int i = 0; i < 5; ++i) {
    int v = i * 4 + slot;
    const float* w1a = W1 + (size_t)(v * 2 + 0) * NDIM;
    const float* w1b = W1 + (size_t)(v * 2 + 1) * NDIM;
    const float* bb1 = b1 + (size_t)v * NDIM;
    const float* w2  = W2 + (size_t)v * NDIM * PDIM;

    float p[6] = {0.f, 0.f, 0.f, 0.f, 0.f, 0.f};
#pragma unroll 4
    for (int h = 0; h < NDIM; ++h) {
      float hv = fmaf(z0, w1a[h], fmaf(z1, w1b[h], bb1[h]));
      hv = hv > 0.f ? hv : 0.f;
#pragma unroll
      for (int j = 0; j < 6; ++j) p[j] = fmaf(hv, w2[h * 6 + j], p[j]);
    }
    float o[6];
#pragma unroll
    for (int j = 0; j < 6; ++j) {
      float t1 = fast_tanh(p[j] + b2[v * PDIM + j]);
      float lo = fmaf(z0, M[v * PDIM + j], z1 * M[VHEADS * PDIM + v * PDIM + j]);
      o[j] = fast_tanh(fmaf(0.15f, lo, t1));
    }
    float* op = orow + v * PDIM;
    f32x2 o01 = {o[0], o[1]};
    f32x2 o23 = {o[2], o[3]};
    f32x2 o45 = {o[4], o[5]};
    __builtin_nontemporal_store(o01, (f32x2*)(op + 0));
    __builtin_nontemporal_store(o23, (f32x2*)(op + 2));
    __builtin_nontemporal_store(o45, (f32x2*)(op + 4));
  }
}

// ---------------------------------------------------------------------------
extern "C" void kernel_launch(void* const* d_in, const int* in_sizes, int n_in,
                              void* d_out, int out_size, void* d_ws, size_t ws_size,
                              hipStream_t stream) {
  const float* x   = (const float*)d_in[0];
  const float* We1 = (const float*)d_in[1];
  const float* be1 = (const float*)d_in[2];
  const float* We2 = (const float*)d_in[3];
  const float* be2 = (const float*)d_in[4];
  const float* W1  = (const float*)d_in[5];
  const float* b1  = (const float*)d_in[6];
  const float* W2  = (const float*)d_in[7];
  const float* b2  = (const float*)d_in[8];
  const float* lA  = (const float*)d_in[9];
  const float* lB  = (const float*)d_in[10];

  float* out  = (float*)d_out;
  float* zout = out + OUT_ELEMS;                       // second tuple output
  unsigned short* wsw = (unsigned short*)d_ws;         // 512 KB bf16 W pack
  float* wsM = (float*)((char*)d_ws + WS_W_BYTES);     // 240 floats

  hipLaunchKernelGGL(k0_pack, dim3(129), dim3(256), 0, stream,
                     We1, lA, lB, wsw, wsM);
  hipLaunchKernelGGL(k1_fused, dim3(BDIM / BM), dim3(64), 0, stream,
                     x, wsw, be1, We2, be2, W1, b1, W2, b2, wsM, out, zout);
}

// Round 13
// 102.695 us; speedup vs baseline: 1.5663x; 1.5663x over previous
//
#include <hip/hip_runtime.h>
#include <hip/hip_bf16.h>
#include <cstdint>
#include <cstddef>

// Problem constants
#define BDIM   32768
#define KDIM   2048
#define NDIM   128
#define VHEADS 20
#define PDIM   6
#define RLORA  10

#define BK      64
#define NCHUNK  (KDIM / BK)                 // 32
#define OUT_ELEMS   (BDIM * VHEADS * PDIM)  // 3932160
#define WS_W_BYTES  (KDIM * NDIM * 2)       // 524288

typedef __attribute__((ext_vector_type(8))) __bf16 bf16x8;
typedef __attribute__((ext_vector_type(4))) float f32x4;
typedef __attribute__((ext_vector_type(2))) float f32x2;
typedef __attribute__((ext_vector_type(4))) unsigned int u32x4;

union FragU { bf16x8 b; u32x4 u; };

__device__ __forceinline__ unsigned int cvt_pk_bf16(float lo, float hi) {
  unsigned int r;
  asm("v_cvt_pk_bf16_f32 %0, %1, %2" : "=v"(r) : "v"(lo), "v"(hi));
  return r;
}

__device__ __forceinline__ void gload_lds16(const void* g, void* l) {
  __builtin_amdgcn_global_load_lds(
      (const __attribute__((address_space(1))) void*)(g),
      (__attribute__((address_space(3))) void*)(l), 16, 0, 0);
}

__device__ __forceinline__ float fast_tanh(float x) {
  float ax = fabsf(x);
  float e  = __expf(-2.0f * ax);
  float t  = __fdividef(1.0f - e, 1.0f + e);
  return copysignf(t, x);
}

// ---------------------------------------------------------------------------
// k0: pack We1 f32[2048][128] -> bf16 in B-FRAGMENT-MAJOR order:
//   n = nt*16 + (lane&15), k = c*64 + ks*32 + (lane>>4)*8 + j.
//   Chunk c = 16 KB at c*16384; fragment (nt,ks) at (nt*2+ks)*1024 + lane*16.
// Also M = lora_A @ lora_B ([2][120]).
// ---------------------------------------------------------------------------
__global__ __launch_bounds__(256)
void k0_pack(const float* __restrict__ We1,
             const float* __restrict__ lA,
             const float* __restrict__ lB,
             unsigned short* __restrict__ wsw,
             float* __restrict__ wsM) {
  if (blockIdx.x == 128) {
    int t = threadIdx.x;
    if (t < 2 * VHEADS * PDIM) {
      int d  = t / (VHEADS * PDIM);
      int vp = t - d * (VHEADS * PDIM);
      float s = 0.f;
#pragma unroll
      for (int r = 0; r < RLORA; ++r)
        s = fmaf(lA[d * RLORA + r], lB[r * (VHEADS * PDIM) + vp], s);
      wsM[t] = s;  // layout [d][vp]
    }
    return;
  }
  int t    = blockIdx.x * 256 + threadIdx.x;  // 0..32767
  int lane = t & 63;
  int blk  = t >> 6;                          // 0..511
  int ks   = blk & 1;
  int nt   = (blk >> 1) & 7;
  int c    = blk >> 4;
  int n    = nt * 16 + (lane & 15);
  int kb   = c * 64 + ks * 32 + (lane >> 4) * 8;

  unsigned int u[4];
#pragma unroll
  for (int q = 0; q < 4; ++q) {
    float f0 = We1[(size_t)(kb + 2 * q + 0) * NDIM + n];
    float f1 = We1[(size_t)(kb + 2 * q + 1) * NDIM + n];
    __hip_bfloat16 h0 = __float2bfloat16(f0);
    __hip_bfloat16 h1 = __float2bfloat16(f1);
    u[q] = (unsigned int)*reinterpret_cast<unsigned short*>(&h0) |
           ((unsigned int)*reinterpret_cast<unsigned short*>(&h1) << 16);
  }
  *reinterpret_cast<u32x4*>(wsw + (size_t)t * 8) = u32x4{u[0], u[1], u[2], u[3]};
}

// ---------------------------------------------------------------------------
// k1: fused encoder + heads.  R5 structure WIDENED to 8 waves (16 waves/CU).
//   512 blocks x 512 thr.  Wave wv = (wr = wv&3 row-group, wc = wv>>2
//   col-half): 16 rows x 64 cols x full K, 8 MFMA/chunk.
//   A: f32 [64][64] chunk via global_load_lds, LINEAR dest, source granule
//      pre-XOR-swizzled (granule s of row r holds global granule s^(r&7)).
//   B: fragment-packed bf16 chunk (16 KB), linear dest.
//   Staging: 4 loads/thread (2 A + 2 B).  Double-buffered, one
//   __syncthreads per chunk (R5-proven).  LDS 66 KB -> 2 blocks/CU.
//   Epilogue: be1/relu/We2 partials, shfl-reduce, cross-col-half LDS
//   combine -> z; fused heads (8 wave-slots; row = lane).
// ---------------------------------------------------------------------------
__global__ __launch_bounds__(512, 4)
void k1_fused(const float* __restrict__ x,
              const unsigned short* __restrict__ wp,
              const float* __restrict__ be1,
              const float* __restrict__ We2,
              const float* __restrict__ be2,
              const float* __restrict__ W1,
              const float* __restrict__ b1,
              const float* __restrict__ W2,
              const float* __restrict__ b2,
              const float* __restrict__ M,
              float* __restrict__ out,
              float* __restrict__ zout) {
  __shared__ char ldsA[2][16384] __attribute__((aligned(16)));
  __shared__ char ldsB[2][16384] __attribute__((aligned(16)));
  __shared__ float zpart2[64][2][2];   // [row][col-half][d]
  __shared__ float zsh[64][2];

  const int tid  = threadIdx.x;        // 0..511
  const int lane = tid & 63;
  const int wv   = tid >> 6;           // 0..7
  const int wr   = wv & 3;             // row-group
  const int wc   = wv >> 2;            // col-half
  const int l15  = lane & 15;
  const int kgrp = lane >> 4;          // 0..3
  const int blk  = blockIdx.x;

  f32x4 acc[4];
#pragma unroll
  for (int i = 0; i < 4; ++i) acc[i] = f32x4{0.f, 0.f, 0.f, 0.f};

  auto STAGE = [&](int b, int c) {
    // A: slots s = tid, tid+512 (row = s>>4, dest granule s&15,
    //    source granule (s&15)^(row&7))
#pragma unroll
    for (int q = 0; q < 2; ++q) {
      int s = tid + q * 512;
      int row = s >> 4;
      int g = (s & 15) ^ (row & 7);
      const float* asrc = x + (size_t)(blk * 64 + row) * KDIM + c * BK + g * 4;
      gload_lds16(asrc, &ldsA[b][s * 16]);
    }
    // B: linear copy of the 16 KB chunk
#pragma unroll
    for (int q = 0; q < 2; ++q) {
      gload_lds16((const char*)wp + (size_t)c * 16384 + q * 8192 + tid * 16,
                  &ldsB[b][q * 8192 + tid * 16]);
    }
  };

  auto COMPUTE = [&](int b) {
    const int row = wr * 16 + l15;
    const char* abase = &ldsA[b][row * 256];
    const int rx = (row & 7) << 4;
    f32x4 A0 = *(const f32x4*)(abase + (((kgrp * 2 + 0) << 4) ^ rx));
    f32x4 A1 = *(const f32x4*)(abase + (((kgrp * 2 + 1) << 4) ^ rx));
    f32x4 A2 = *(const f32x4*)(abase + 128 + (((kgrp * 2 + 0) << 4) ^ rx));
    f32x4 A3 = *(const f32x4*)(abase + 128 + (((kgrp * 2 + 1) << 4) ^ rx));
    FragU a0, a1;
    a0.u = u32x4{cvt_pk_bf16(A0.x, A0.y), cvt_pk_bf16(A0.z, A0.w),
                 cvt_pk_bf16(A1.x, A1.y), cvt_pk_bf16(A1.z, A1.w)};
    a1.u = u32x4{cvt_pk_bf16(A2.x, A2.y), cvt_pk_bf16(A2.z, A2.w),
                 cvt_pk_bf16(A3.x, A3.y), cvt_pk_bf16(A3.z, A3.w)};
    const char* bbase = &ldsB[b][lane * 16];
#pragma unroll
    for (int nt = 0; nt < 4; ++nt) {
      FragU b0, b1;
      b0.u = *(const u32x4*)(bbase + ((wc * 4 + nt) * 2 + 0) * 1024);
      b1.u = *(const u32x4*)(bbase + ((wc * 4 + nt) * 2 + 1) * 1024);
      acc[nt] = __builtin_amdgcn_mfma_f32_16x16x32_bf16(a0.b, b0.b, acc[nt], 0, 0, 0);
      acc[nt] = __builtin_amdgcn_mfma_f32_16x16x32_bf16(a1.b, b1.b, acc[nt], 0, 0, 0);
    }
  };

  // prologue
  STAGE(0, 0);
  __syncthreads();

#pragma unroll 1
  for (int c = 0; c < NCHUNK; ++c) {
    int b = c & 1;
    if (c + 1 < NCHUNK) STAGE(b ^ 1, c + 1);
    COMPUTE(b);
    __syncthreads();
  }

  // ---- epilogue: +be1, relu, @We2 partials (this wave's 64 cols)
  float part[4][2];
#pragma unroll
  for (int j = 0; j < 4; ++j) { part[j][0] = 0.f; part[j][1] = 0.f; }
#pragma unroll
  for (int nt = 0; nt < 4; ++nt) {
    int col = (wc * 4 + nt) * 16 + l15;
    float bb = be1[col];
    float w0 = We2[col * 2 + 0];
    float w1 = We2[col * 2 + 1];
#pragma unroll
    for (int j = 0; j < 4; ++j) {
      float h = acc[nt][j] + bb;
      h = h > 0.f ? h : 0.f;
      part[j][0] = fmaf(h, w0, part[j][0]);
      part[j][1] = fmaf(h, w1, part[j][1]);
    }
  }
#pragma unroll
  for (int m = 1; m < 16; m <<= 1) {
#pragma unroll
    for (int j = 0; j < 4; ++j) {
      part[j][0] += __shfl_xor(part[j][0], m, 64);
      part[j][1] += __shfl_xor(part[j][1], m, 64);
    }
  }
  if (l15 == 0) {
#pragma unroll
    for (int j = 0; j < 4; ++j) {
      int rl = wr * 16 + kgrp * 4 + j;   // C row = (lane>>4)*4 + reg
      zpart2[rl][wc][0] = part[j][0];
      zpart2[rl][wc][1] = part[j][1];
    }
  }
  __syncthreads();
  if (tid < 64) {
    float s0 = zpart2[tid][0][0] + zpart2[tid][1][0] + be2[0];
    float s1 = zpart2[tid][0][1] + zpart2[tid][1][1] + be2[1];
    zsh[tid][0] = s0;
    zsh[tid][1] = s1;
    f32x2 zz = {s0, s1};
    *(f32x2*)(zout + (size_t)(blk * 64 + tid) * 2) = zz;
  }
  __syncthreads();

  // ---- heads: row = lane, head slots per wave: wv, wv+8, (wv<4: wv+16)
  const int wvu = __builtin_amdgcn_readfirstlane(wv);
  float z0 = zsh[lane][0];
  float z1 = zsh[lane][1];
  float* orow = out + (size_t)(blk * 64 + lane) * (VHEADS * PDIM);

  auto head = [&](int v) {
    const float* w1a = W1 + (size_t)(v * 2 + 0) * NDIM;
    const float* w1b = W1 + (size_t)(v * 2 + 1) * NDIM;
    const float* bb1 = b1 + (size_t)v * NDIM;
    const float* w2  = W2 + (size_t)v * NDIM * PDIM;

    float p[6] = {0.f, 0.f, 0.f, 0.f, 0.f, 0.f};
#pragma unroll 4
    for (int h = 0; h < NDIM; ++h) {
      float hv = fmaf(z0, w1a[h], fmaf(z1, w1b[h], bb1[h]));
      hv = hv > 0.f ? hv : 0.f;
#pragma unroll
      for (int j = 0; j < 6; ++j) p[j] = fmaf(hv, w2[h * 6 + j], p[j]);
    }
    float o[6];
#pragma unroll
    for (int j = 0; j < 6; ++j) {
      float t1 = fast_tanh(p[j] + b2[v * PDIM + j]);
      float lo = fmaf(z0, M[v * PDIM + j], z1 * M[VHEADS * PDIM + v * PDIM + j]);
      o[j] = fast_tanh(fmaf(0.15f, lo, t1));
    }
    float* op = orow + v * PDIM;
    f32x2 o01 = {o[0], o[1]};
    f32x2 o23 = {o[2], o[3]};
    f32x2 o45 = {o[4], o[5]};
    __builtin_nontemporal_store(o01, (f32x2*)(op + 0));
    __builtin_nontemporal_store(o23, (f32x2*)(op + 2));
    __builtin_nontemporal_store(o45, (f32x2*)(op + 4));
  };

  head(wvu);
  head(wvu + 8);
  if (wvu < 4) head(wvu + 16);
}

// ---------------------------------------------------------------------------
extern "C" void kernel_launch(void* const* d_in, const int* in_sizes, int n_in,
                              void* d_out, int out_size, void* d_ws, size_t ws_size,
                              hipStream_t stream) {
  const float* x   = (const float*)d_in[0];
  const float* We1 = (const float*)d_in[1];
  const float* be1 = (const float*)d_in[2];
  const float* We2 = (const float*)d_in[3];
  const float* be2 = (const float*)d_in[4];
  const float* W1  = (const float*)d_in[5];
  const float* b1  = (const float*)d_in[6];
  const float* W2  = (const float*)d_in[7];
  const float* b2  = (const float*)d_in[8];
  const float* lA  = (const float*)d_in[9];
  const float* lB  = (const float*)d_in[10];

  float* out  = (float*)d_out;
  float* zout = out + OUT_ELEMS;                       // second tuple output
  unsigned short* wsw = (unsigned short*)d_ws;         // 512 KB bf16 W pack
  float* wsM = (float*)((char*)d_ws + WS_W_BYTES);     // 240 floats

  hipLaunchKernelGGL(k0_pack, dim3(129), dim3(256), 0, stream,
                     We1, lA, lB, wsw, wsM);
  hipLaunchKernelGGL(k1_fused, dim3(BDIM / 64), dim3(512), 0, stream,
                     x, wsw, be1, We2, be2, W1, b1, W2, b2, wsM, out, zout);
}

// Round 14
// 95.724 us; speedup vs baseline: 1.6803x; 1.0728x over previous
//
#include <hip/hip_runtime.h>
#include <hip/hip_bf16.h>
#include <cstdint>
#include <cstddef>

// Problem constants
#define BDIM   32768
#define KDIM   2048
#define NDIM   128
#define VHEADS 20
#define PDIM   6
#define RLORA  10

#define BK      64
#define NCHUNK  (KDIM / BK)                 // 32
#define OUT_ELEMS   (BDIM * VHEADS * PDIM)  // 3932160
#define WS_W_BYTES  (KDIM * NDIM * 2)       // 524288

typedef __attribute__((ext_vector_type(8))) __bf16 bf16x8;
typedef __attribute__((ext_vector_type(4))) float f32x4;
typedef __attribute__((ext_vector_type(2))) float f32x2;
typedef __attribute__((ext_vector_type(4))) unsigned int u32x4;

union FragU { bf16x8 b; u32x4 u; };

__device__ __forceinline__ unsigned int cvt_pk_bf16(float lo, float hi) {
  unsigned int r;
  asm("v_cvt_pk_bf16_f32 %0, %1, %2" : "=v"(r) : "v"(lo), "v"(hi));
  return r;
}

__device__ __forceinline__ void gload_lds16(const void* g, void* l) {
  __builtin_amdgcn_global_load_lds(
      (const __attribute__((address_space(1))) void*)(g),
      (__attribute__((address_space(3))) void*)(l), 16, 0, 0);
}

__device__ __forceinline__ float fast_tanh(float x) {
  float ax = fabsf(x);
  float e  = __expf(-2.0f * ax);
  float t  = __fdividef(1.0f - e, 1.0f + e);
  return copysignf(t, x);
}

#define SBAR() __builtin_amdgcn_sched_barrier(0)

// ---------------------------------------------------------------------------
// k0: pack We1 f32[2048][128] -> bf16 in B-FRAGMENT-MAJOR order:
//   n = nt*16 + (lane&15), k = c*64 + ks*32 + (lane>>4)*8 + j.
//   Chunk c = 16 KB at c*16384; fragment (nt,ks) at (nt*2+ks)*1024 + lane*16.
// Also M = lora_A @ lora_B ([2][120]).
// ---------------------------------------------------------------------------
__global__ __launch_bounds__(256)
void k0_pack(const float* __restrict__ We1,
             const float* __restrict__ lA,
             const float* __restrict__ lB,
             unsigned short* __restrict__ wsw,
             float* __restrict__ wsM) {
  if (blockIdx.x == 128) {
    int t = threadIdx.x;
    if (t < 2 * VHEADS * PDIM) {
      int d  = t / (VHEADS * PDIM);
      int vp = t - d * (VHEADS * PDIM);
      float s = 0.f;
#pragma unroll
      for (int r = 0; r < RLORA; ++r)
        s = fmaf(lA[d * RLORA + r], lB[r * (VHEADS * PDIM) + vp], s);
      wsM[t] = s;  // layout [d][vp]
    }
    return;
  }
  int t    = blockIdx.x * 256 + threadIdx.x;  // 0..32767
  int lane = t & 63;
  int blk  = t >> 6;                          // 0..511
  int ks   = blk & 1;
  int nt   = (blk >> 1) & 7;
  int c    = blk >> 4;
  int n    = nt * 16 + (lane & 15);
  int kb   = c * 64 + ks * 32 + (lane >> 4) * 8;

  unsigned int u[4];
#pragma unroll
  for (int q = 0; q < 4; ++q) {
    float f0 = We1[(size_t)(kb + 2 * q + 0) * NDIM + n];
    float f1 = We1[(size_t)(kb + 2 * q + 1) * NDIM + n];
    __hip_bfloat16 h0 = __float2bfloat16(f0);
    __hip_bfloat16 h1 = __float2bfloat16(f1);
    u[q] = (unsigned int)*reinterpret_cast<unsigned short*>(&h0) |
           ((unsigned int)*reinterpret_cast<unsigned short*>(&h1) << 16);
  }
  *reinterpret_cast<u32x4*>(wsw + (size_t)t * 8) = u32x4{u[0], u[1], u[2], u[3]};
}

// ---------------------------------------------------------------------------
// k1: fused encoder + heads.  R13 geometry + COUNTED-VMCNT pipeline:
//   512 blocks x 512 thr (8 waves: wr = wv&3 row-group x16, wc = wv>>2
//   col-half x64).  STATIC double-buffers (A0_/A1_/B0_/B1_ as distinct
//   __shared__ arrays, loop unrolled x2) so SIInsertWaitcnts can prove
//   ds_reads don't alias in-flight DMA -> our counted s_waitcnt vmcnt(4)
//   sticks (4 loads/thread/chunk; next chunk's 4 stay in flight ACROSS
//   both raw s_barriers -- never drain to 0 in steady state).
//   A: f32 [64][64] via global_load_lds, linear dest, source granule
//      pre-XOR-swizzled (granule s of row r = global granule s^(r&7)).
//   B: fragment-packed bf16 (16 KB/chunk), linear dest.
//   Epilogue: be1/relu/We2 partials, shfl-reduce, cross-half combine -> z;
//   fused heads (8 wave-slots; row = lane).
// ---------------------------------------------------------------------------
__global__ __launch_bounds__(512, 4)
void k1_fused(const float* __restrict__ x,
              const unsigned short* __restrict__ wp,
              const float* __restrict__ be1,
              const float* __restrict__ We2,
              const float* __restrict__ be2,
              const float* __restrict__ W1,
              const float* __restrict__ b1,
              const float* __restrict__ W2,
              const float* __restrict__ b2,
              const float* __restrict__ M,
              float* __restrict__ out,
              float* __restrict__ zout) {
  __shared__ char A0_[16384] __attribute__((aligned(16)));
  __shared__ char A1_[16384] __attribute__((aligned(16)));
  __shared__ char B0_[16384] __attribute__((aligned(16)));
  __shared__ char B1_[16384] __attribute__((aligned(16)));
  __shared__ float zpart2[64][2][2];   // [row][col-half][d]
  __shared__ float zsh[64][2];

  const int tid  = threadIdx.x;        // 0..511
  const int lane = tid & 63;
  const int wv   = tid >> 6;           // 0..7
  const int wr   = wv & 3;             // row-group
  const int wc   = wv >> 2;            // col-half
  const int l15  = lane & 15;
  const int kgrp = lane >> 4;          // 0..3
  const int blk  = blockIdx.x;

  f32x4 acc[4];
#pragma unroll
  for (int i = 0; i < 4; ++i) acc[i] = f32x4{0.f, 0.f, 0.f, 0.f};

  auto STAGE = [&](char* Ad, char* Bd, int c) {
    // A: slots s = tid, tid+512 (row = s>>4, dest granule s&15,
    //    source granule (s&15)^(row&7))
#pragma unroll
    for (int q = 0; q < 2; ++q) {
      int s = tid + q * 512;
      int row = s >> 4;
      int g = (s & 15) ^ (row & 7);
      const float* asrc = x + (size_t)(blk * 64 + row) * KDIM + c * BK + g * 4;
      gload_lds16(asrc, Ad + s * 16);
    }
    // B: linear copy of the 16 KB chunk
#pragma unroll
    for (int q = 0; q < 2; ++q) {
      gload_lds16((const char*)wp + (size_t)c * 16384 + q * 8192 + tid * 16,
                  Bd + q * 8192 + tid * 16);
    }
  };

  auto COMPUTE = [&](const char* Ad, const char* Bd) {
    const int row = wr * 16 + l15;
    const char* abase = Ad + row * 256;
    const int rx = (row & 7) << 4;
    f32x4 A0 = *(const f32x4*)(abase + (((kgrp * 2 + 0) << 4) ^ rx));
    f32x4 A1 = *(const f32x4*)(abase + (((kgrp * 2 + 1) << 4) ^ rx));
    f32x4 A2 = *(const f32x4*)(abase + 128 + (((kgrp * 2 + 0) << 4) ^ rx));
    f32x4 A3 = *(const f32x4*)(abase + 128 + (((kgrp * 2 + 1) << 4) ^ rx));
    FragU a0, a1;
    a0.u = u32x4{cvt_pk_bf16(A0.x, A0.y), cvt_pk_bf16(A0.z, A0.w),
                 cvt_pk_bf16(A1.x, A1.y), cvt_pk_bf16(A1.z, A1.w)};
    a1.u = u32x4{cvt_pk_bf16(A2.x, A2.y), cvt_pk_bf16(A2.z, A2.w),
                 cvt_pk_bf16(A3.x, A3.y), cvt_pk_bf16(A3.z, A3.w)};
    const char* bbase = Bd + lane * 16;
#pragma unroll
    for (int nt = 0; nt < 4; ++nt) {
      FragU b0, b1;
      b0.u = *(const u32x4*)(bbase + ((wc * 4 + nt) * 2 + 0) * 1024);
      b1.u = *(const u32x4*)(bbase + ((wc * 4 + nt) * 2 + 1) * 1024);
      acc[nt] = __builtin_amdgcn_mfma_f32_16x16x32_bf16(a0.b, b0.b, acc[nt], 0, 0, 0);
      acc[nt] = __builtin_amdgcn_mfma_f32_16x16x32_bf16(a1.b, b1.b, acc[nt], 0, 0, 0);
    }
  };

  // prologue: chunks 0,1 in flight (8 loads/thread)
  STAGE(A0_, B0_, 0);
  STAGE(A1_, B1_, 1);

#pragma unroll 1
  for (int cc = 0; cc < NCHUNK / 2 - 1; ++cc) {   // computes 2cc, 2cc+1
    asm volatile("s_waitcnt vmcnt(4)" ::: "memory");   // chunk 2cc landed
    SBAR();
    __builtin_amdgcn_s_barrier();
    COMPUTE(A0_, B0_);
    __builtin_amdgcn_s_barrier();
    SBAR();
    STAGE(A0_, B0_, 2 * cc + 2);                       // back to 8 in flight
    asm volatile("s_waitcnt vmcnt(4)" ::: "memory");   // chunk 2cc+1 landed
    SBAR();
    __builtin_amdgcn_s_barrier();
    COMPUTE(A1_, B1_);
    __builtin_amdgcn_s_barrier();
    SBAR();
    STAGE(A1_, B1_, 2 * cc + 3);
  }
  // tail: chunks 30, 31 (no further staging)
  asm volatile("s_waitcnt vmcnt(4)" ::: "memory");
  SBAR();
  __builtin_amdgcn_s_barrier();
  COMPUTE(A0_, B0_);
  asm volatile("s_waitcnt vmcnt(0)" ::: "memory");
  SBAR();
  __builtin_amdgcn_s_barrier();
  COMPUTE(A1_, B1_);

  // ---- epilogue: +be1, relu, @We2 partials (this wave's 64 cols)
  float part[4][2];
#pragma unroll
  for (int j = 0; j < 4; ++j) { part[j][0] = 0.f; part[j][1] = 0.f; }
#pragma unroll
  for (int nt = 0; nt < 4; ++nt) {
    int col = (wc * 4 + nt) * 16 + l15;
    float bb = be1[col];
    float w0 = We2[col * 2 + 0];
    float w1 = We2[col * 2 + 1];
#pragma unroll
    for (int j = 0; j < 4; ++j) {
      float h = acc[nt][j] + bb;
      h = h > 0.f ? h : 0.f;
      part[j][0] = fmaf(h, w0, part[j][0]);
      part[j][1] = fmaf(h, w1, part[j][1]);
    }
  }
#pragma unroll
  for (int m = 1; m < 16; m <<= 1) {
#pragma unroll
    for (int j = 0; j < 4; ++j) {
      part[j][0] += __shfl_xor(part[j][0], m, 64);
      part[j][1] += __shfl_xor(part[j][1], m, 64);
    }
  }
  if (l15 == 0) {
#pragma unroll
    for (int j = 0; j < 4; ++j) {
      int rl = wr * 16 + kgrp * 4 + j;   // C row = (lane>>4)*4 + reg
      zpart2[rl][wc][0] = part[j][0];
      zpart2[rl][wc][1] = part[j][1];
    }
  }
  __syncthreads();
  if (tid < 64) {
    float s0 = zpart2[tid][0][0] + zpart2[tid][1][0] + be2[0];
    float s1 = zpart2[tid][0][1] + zpart2[tid][1][1] + be2[1];
    zsh[tid][0] = s0;
    zsh[tid][1] = s1;
    f32x2 zz = {s0, s1};
    *(f32x2*)(zout + (size_t)(blk * 64 + tid) * 2) = zz;
  }
  __syncthreads();

  // ---- heads: row = lane, head slots per wave: wv, wv+8, (wv<4: wv+16)
  const int wvu = __builtin_amdgcn_readfirstlane(wv);
  float z0 = zsh[lane][0];
  float z1 = zsh[lane][1];
  float* orow = out + (size_t)(blk * 64 + lane) * (VHEADS * PDIM);

  auto head = [&](int v) {
    const float* w1a = W1 + (size_t)(v * 2 + 0) * NDIM;
    const float* w1b = W1 + (size_t)(v * 2 + 1) * NDIM;
    const float* bb1 = b1 + (size_t)v * NDIM;
    const float* w2  = W2 + (size_t)v * NDIM * PDIM;

    float p[6] = {0.f, 0.f, 0.f, 0.f, 0.f, 0.f};
#pragma unroll 4
    for (int h = 0; h < NDIM; ++h) {
      float hv = fmaf(z0, w1a[h], fmaf(z1, w1b[h], bb1[h]));
      hv = hv > 0.f ? hv : 0.f;
#pragma unroll
      for (int j = 0; j < 6; ++j) p[j] = fmaf(hv, w2[h * 6 + j], p[j]);
    }
    float o[6];
#pragma unroll
    for (int j = 0; j < 6; ++j) {
      float t1 = fast_tanh(p[j] + b2[v * PDIM + j]);
      float lo = fmaf(z0, M[v * PDIM + j], z1 * M[VHEADS * PDIM + v * PDIM + j]);
      o[j] = fast_tanh(fmaf(0.15f, lo, t1));
    }
    float* op = orow + v * PDIM;
    f32x2 o01 = {o[0], o[1]};
    f32x2 o23 = {o[2], o[3]};
    f32x2 o45 = {o[4], o[5]};
    __builtin_nontemporal_store(o01, (f32x2*)(op + 0));
    __builtin_nontemporal_store(o23, (f32x2*)(op + 2));
    __builtin_nontemporal_store(o45, (f32x2*)(op + 4));
  };

  head(wvu);
  head(wvu + 8);
  if (wvu < 4) head(wvu + 16);
}

// ---------------------------------------------------------------------------
extern "C" void kernel_launch(void* const* d_in, const int* in_sizes, int n_in,
                              void* d_out, int out_size, void* d_ws, size_t ws_size,
                              hipStream_t stream) {
  const float* x   = (const float*)d_in[0];
  const float* We1 = (const float*)d_in[1];
  const float* be1 = (const float*)d_in[2];
  const float* We2 = (const float*)d_in[3];
  const float* be2 = (const float*)d_in[4];
  const float* W1  = (const float*)d_in[5];
  const float* b1  = (const float*)d_in[6];
  const float* W2  = (const float*)d_in[7];
  const float* b2  = (const float*)d_in[8];
  const float* lA  = (const float*)d_in[9];
  const float* lB  = (const float*)d_in[10];

  float* out  = (float*)d_out;
  float* zout = out + OUT_ELEMS;                       // second tuple output
  unsigned short* wsw = (unsigned short*)d_ws;         // 512 KB bf16 W pack
  float* wsM = (float*)((char*)d_ws + WS_W_BYTES);     // 240 floats

  hipLaunchKernelGGL(k0_pack, dim3(129), dim3(256), 0, stream,
                     We1, lA, lB, wsw, wsM);
  hipLaunchKernelGGL(k1_fused, dim3(BDIM / 64), dim3(512), 0, stream,
                     x, wsw, be1, We2, be2, W1, b1, W2, b2, wsM, out, zout);
}